// Round 8
// baseline (172.089 us; speedup 1.0000x reference)
//
#include <hip/hip_runtime.h>

#define GRID_H 20
#define GRID_W 80
#define NCH 264
#define K 256
#define NPIX 128   // 16x8 glyph pixels

typedef __attribute__((ext_vector_type(8))) short short8;
typedef __attribute__((ext_vector_type(4))) float f32x4;
typedef __attribute__((ext_vector_type(8))) unsigned short u16x8;

static __device__ __forceinline__ unsigned short f2bf(float f) {
    unsigned int u = __builtin_bit_cast(unsigned int, f);
    u += 0x7FFFu + ((u >> 16) & 1u);   // round-to-nearest-even
    return (unsigned short)(u >> 16);
}

// NOTE: no min-waves-per-EU arg. Every failing round (R2/R3/R7) had one;
// every passing round lacked it. LDS (35.3KB) alone gives 4 blocks/CU.
__global__ __launch_bounds__(320) void ansi_kernel(
        const float* __restrict__ data,
        const float* __restrict__ cm,
        float* __restrict__ out) {
    // 32 KB: one PIXEL-half of B (64 pixels x 256 channels, bf16, swizzled).
    // Rows are 512B (full K) — identical layout/swizzle to the passing R6
    // kernel, just 64 rows instead of 128. Reused as output staging.
    __shared__ alignas(16) unsigned short Bl[64 * K];
    __shared__ float fgbg[GRID_W * 8];   // per cell: bg.rgb, (fg-bg).rgb

    const int blk = blockIdx.x;
    const int b = blk / GRID_H;
    const int h = blk % GRID_H;
    const float* dbase = data + (size_t)(b * GRID_H + h) * GRID_W * NCH;
    const int t = threadIdx.x;
    const int wave = t >> 6;
    const int lane = t & 63;
    const int mrow = lane & 15;     // cell within M-tile / pixel within N-tile
    const int g    = lane >> 4;     // k-group
    const int cell0 = wave * 16;

    // ---- stage per-cell fg/bg -> (bg, fg-bg) ----
    for (int w = t; w < GRID_W; w += 320) {
        const float* q = dbase + (size_t)w * NCH + 256;
        float4 a = *reinterpret_cast<const float4*>(q);      // fg_bold, fg.rgb
        float4 c = *reinterpret_cast<const float4*>(q + 4);  // bg_bold, bg.rgb
        float fs = 0.5f * a.x + 0.5f;
        float bs = 0.5f * c.x + 0.5f;
        float bgr = bs * c.y, bgg = bs * c.z, bgb = bs * c.w;
        float* o = &fgbg[w * 8];
        o[0] = bgr; o[1] = bgg; o[2] = bgb;
        o[3] = fs * a.y - bgr; o[4] = fs * a.z - bgg; o[5] = fs * a.w - bgb;
    }

    // ---- load + pack A once (full K=256): 8 x bf16x8 = 16 VGPRs ----
    const float* arow = dbase + (size_t)(cell0 + mrow) * NCH + g * 8;
    short8 apk[8];
    #pragma unroll
    for (int ks = 0; ks < 8; ++ks) {
        float4 a0 = *reinterpret_cast<const float4*>(arow + ks * 32);
        float4 a1 = *reinterpret_cast<const float4*>(arow + ks * 32 + 4);
        u16x8 ap;
        ap[0] = f2bf(a0.x); ap[1] = f2bf(a0.y); ap[2] = f2bf(a0.z); ap[3] = f2bf(a0.w);
        ap[4] = f2bf(a1.x); ap[5] = f2bf(a1.y); ap[6] = f2bf(a1.z); ap[7] = f2bf(a1.w);
        apk[ks] = __builtin_bit_cast(short8, ap);
    }

    f32x4 acc[8];
    #pragma unroll
    for (int n = 0; n < 8; ++n) acc[n] = (f32x4){0.f, 0.f, 0.f, 0.f};

    #pragma unroll
    for (int half = 0; half < 2; ++half) {
        // ---- stage pixel-half: pixels half*64 + (0..63), all 256 channels ----
        for (int i = t; i < 64 * 32; i += 320) {
            int pl = i & 63;                  // local pixel row
            int cg = i >> 6;                  // channel group of 8 (0..31)
            const float* src = cm + (size_t)cg * 8 * NPIX + half * 64 + pl;
            u16x8 pk;
            #pragma unroll
            for (int j = 0; j < 8; ++j) pk[j] = f2bf(src[j * NPIX]);
            int ba = (pl * 512 + cg * 16) ^ ((pl & 7) << 4);
            *reinterpret_cast<u16x8*>(reinterpret_cast<char*>(Bl) + ba) = pk;
        }
        __syncthreads();   // staging (and, for half=0, fgbg) visible

        // ---- GEMM: exact R6 inner loop, n restricted to this pixel-half ----
        #pragma unroll
        for (int ks = 0; ks < 8; ++ks) {
            const int kbase = ks * 32 + g * 8;
            #pragma unroll
            for (int n = 0; n < 4; ++n) {
                int pl = n * 16 + mrow;       // local pixel row 0..63
                int ba = (pl * 512 + kbase * 2) ^ ((pl & 7) << 4);
                short8 bfrag = *reinterpret_cast<short8*>(
                    reinterpret_cast<char*>(Bl) + ba);
                acc[half * 4 + n] = __builtin_amdgcn_mfma_f32_16x16x32_bf16(
                    apk[ks], bfrag, acc[half * 4 + n], 0, 0, 0);
            }
        }
        __syncthreads();   // all waves done reading Bl before restage/reuse
    }

    // ---- epilogue (EXACT R6): out = bg + raw*(fg-bg), LDS-staged stores ----
    const int col = lane & 15;
    const int rowbase = (lane >> 4) << 2;

    float bgv[4][3], dv[4][3];
    #pragma unroll
    for (int r = 0; r < 4; ++r) {
        const float* fb = &fgbg[(cell0 + rowbase + r) * 8];
        bgv[r][0] = fb[0]; bgv[r][1] = fb[1]; bgv[r][2] = fb[2];
        dv[r][0]  = fb[3]; dv[r][1]  = fb[4]; dv[r][2]  = fb[5];
    }

    float* S = (float*)Bl;   // 4 y-lines: 4*640*3 floats = 30720B < 32KB
    const size_t blockbase = ((size_t)b * 320 + h * 16) * 640 * 3;

    #pragma unroll
    for (int pass = 0; pass < 4; ++pass) {
        #pragma unroll
        for (int dn = 0; dn < 2; ++dn) {
            int n = pass * 2 + dn;              // static under unroll
            int pix = n * 16 + col;             // global pixel = acc-index*16+col
            int yy = dn * 2 + (col >> 3);       // y-line within staging buffer
            int x = pix & 7;
            #pragma unroll
            for (int r = 0; r < 4; ++r) {
                int cell = cell0 + rowbase + r;
                float raw = acc[n][r];
                float* o = &S[(yy * 640 + cell * 8 + x) * 3];
                o[0] = bgv[r][0] + raw * dv[r][0];
                o[1] = bgv[r][1] + raw * dv[r][1];
                o[2] = bgv[r][2] + raw * dv[r][2];
            }
        }
        __syncthreads();
        // 7680 floats = 1920 float4 = 6 per thread, fully coalesced
        float4* od = (float4*)(out + blockbase + (size_t)pass * 7680);
        const float4* Sv = (const float4*)S;
        #pragma unroll
        for (int q = 0; q < 6; ++q) {
            int j = q * 320 + t;
            od[j] = Sv[j];
        }
        __syncthreads();   // before next pass overwrites S
    }
}

extern "C" void kernel_launch(void* const* d_in, const int* in_sizes, int n_in,
                              void* d_out, int out_size, void* d_ws, size_t ws_size,
                              hipStream_t stream) {
    (void)in_sizes; (void)n_in; (void)d_ws; (void)ws_size; (void)out_size;
    const float* data = (const float*)d_in[0];
    const float* cm   = (const float*)d_in[1];
    float* out        = (float*)d_out;
    const int nblocks = 128 * GRID_H;   // one block per (b, h)
    ansi_kernel<<<nblocks, 320, 0, stream>>>(data, cm, out);
}

// Round 9
// 136.470 us; speedup vs baseline: 1.2610x; 1.2610x over previous
//
#include <hip/hip_runtime.h>

#define GRID_H 20
#define GRID_W 80
#define NCH 264
#define K 256
#define NPIX 128   // 16x8 glyph pixels

typedef __attribute__((ext_vector_type(8))) short short8;
typedef __attribute__((ext_vector_type(4))) float f32x4;
typedef __attribute__((ext_vector_type(8))) unsigned short u16x8;

static __device__ __forceinline__ unsigned short f2bf(float f) {
    unsigned int u = __builtin_bit_cast(unsigned int, f);
    u += 0x7FFFu + ((u >> 16) & 1u);   // round-to-nearest-even
    return (unsigned short)(u >> 16);
}

// NOTE: plain 1-arg launch_bounds only. The 2-arg form (min waves/EU) made
// R2/R3/R7 miscompile (part of the MFMA accumulation dropped).
__global__ __launch_bounds__(320) void ansi_kernel(
        const float* __restrict__ data,
        const float* __restrict__ cm,
        float* __restrict__ out) {
    // 32 KB: one PIXEL-half of B (64 px rows x 256 ch, bf16, swizzled) — R8 layout.
    __shared__ alignas(16) unsigned short Bl[64 * K];
    // Wave-PRIVATE epilogue staging: [wave][line(2)][cell-slot(16)][x*3+ch(24)].
    // Cells stored at transposed slot (c&3)*4+(c>>2) -> conflict-free writes;
    // 24 floats/cell = 6 aligned float4 -> pure b128 readback.
    __shared__ alignas(16) float S[5][2][16][24];
    __shared__ float fgbg[GRID_W * 8];   // per cell: bg.rgb, (fg-bg).rgb

    const int blk = blockIdx.x;
    const int b = blk / GRID_H;
    const int h = blk % GRID_H;
    const float* dbase = data + (size_t)(b * GRID_H + h) * GRID_W * NCH;
    const int t = threadIdx.x;
    const int wave = t >> 6;
    const int lane = t & 63;
    const int mrow = lane & 15;     // cell within M-tile / pixel within N-tile
    const int g    = lane >> 4;     // k-group
    const int cell0 = wave * 16;

    // ---- stage per-cell fg/bg -> (bg, fg-bg) ----
    for (int w = t; w < GRID_W; w += 320) {
        const float* q = dbase + (size_t)w * NCH + 256;
        float4 a = *reinterpret_cast<const float4*>(q);      // fg_bold, fg.rgb
        float4 c = *reinterpret_cast<const float4*>(q + 4);  // bg_bold, bg.rgb
        float fs = 0.5f * a.x + 0.5f;
        float bs = 0.5f * c.x + 0.5f;
        float bgr = bs * c.y, bgg = bs * c.z, bgb = bs * c.w;
        float* o = &fgbg[w * 8];
        o[0] = bgr; o[1] = bgg; o[2] = bgb;
        o[3] = fs * a.y - bgr; o[4] = fs * a.z - bgg; o[5] = fs * a.w - bgb;
    }

    // ---- load + pack A once (full K=256): 8 x bf16x8 ----
    const float* arow = dbase + (size_t)(cell0 + mrow) * NCH + g * 8;
    short8 apk[8];
    #pragma unroll
    for (int ks = 0; ks < 8; ++ks) {
        float4 a0 = *reinterpret_cast<const float4*>(arow + ks * 32);
        float4 a1 = *reinterpret_cast<const float4*>(arow + ks * 32 + 4);
        u16x8 ap;
        ap[0] = f2bf(a0.x); ap[1] = f2bf(a0.y); ap[2] = f2bf(a0.z); ap[3] = f2bf(a0.w);
        ap[4] = f2bf(a1.x); ap[5] = f2bf(a1.y); ap[6] = f2bf(a1.z); ap[7] = f2bf(a1.w);
        apk[ks] = __builtin_bit_cast(short8, ap);
    }

    f32x4 acc[8];
    #pragma unroll
    for (int n = 0; n < 8; ++n) acc[n] = (f32x4){0.f, 0.f, 0.f, 0.f};

    // ---- GEMM over two pixel-halves; 3 barriers total ----
    #pragma unroll
    for (int half = 0; half < 2; ++half) {
        for (int i = t; i < 64 * 32; i += 320) {
            int pl = i & 63;                  // local pixel row
            int cg = i >> 6;                  // channel group of 8 (0..31)
            const float* src = cm + (size_t)cg * 8 * NPIX + half * 64 + pl;
            u16x8 pk;
            #pragma unroll
            for (int j = 0; j < 8; ++j) pk[j] = f2bf(src[j * NPIX]);
            int ba = (pl * 512 + cg * 16) ^ ((pl & 7) << 4);
            *reinterpret_cast<u16x8*>(reinterpret_cast<char*>(Bl) + ba) = pk;
        }
        __syncthreads();   // staging (and, for half=0, fgbg) visible

        #pragma unroll
        for (int ks = 0; ks < 8; ++ks) {
            const int kbase = ks * 32 + g * 8;
            #pragma unroll
            for (int n = 0; n < 4; ++n) {
                int pl = n * 16 + mrow;       // local pixel row 0..63
                int ba = (pl * 512 + kbase * 2) ^ ((pl & 7) << 4);
                short8 bfrag = *reinterpret_cast<short8*>(
                    reinterpret_cast<char*>(Bl) + ba);
                acc[half * 4 + n] = __builtin_amdgcn_mfma_f32_16x16x32_bf16(
                    apk[ks], bfrag, acc[half * 4 + n], 0, 0, 0);
            }
        }
        if (half == 0) __syncthreads();   // all waves done reading Bl before restage
    }

    // ---- epilogue: wave-private LDS transpose, ZERO barriers ----
    const int col = lane & 15;

    float bgv[4][3], dv[4][3];
    #pragma unroll
    for (int r = 0; r < 4; ++r) {
        const float* fb = &fgbg[(cell0 + g * 4 + r) * 8];
        bgv[r][0] = fb[0]; bgv[r][1] = fb[1]; bgv[r][2] = fb[2];
        dv[r][0]  = fb[3]; dv[r][1]  = fb[4]; dv[r][2]  = fb[5];
    }

    float4* out4 = (float4*)out;
    // float4 index of (row y=0 of this (b,h), this wave's 16 cells)
    const size_t rowf4 = (size_t)(b * 320 + h * 16) * 480 + wave * 96;
    const int line_sel = col >> 3;          // which y-line this lane's acc feeds
    const int x3 = (col & 7) * 3;

    #pragma unroll
    for (int pass = 0; pass < 8; ++pass) {
        // write: acc[pass] covers pixels pass*16..pass*16+15 = y-lines {2p,2p+1}
        #pragma unroll
        for (int r = 0; r < 4; ++r) {
            float raw = acc[pass][r];
            float* o = &S[wave][line_sel][r * 4 + g][x3];
            o[0] = bgv[r][0] + raw * dv[r][0];
            o[1] = bgv[r][1] + raw * dv[r][1];
            o[2] = bgv[r][2] + raw * dv[r][2];
        }
        // readback (b128, permuted cell slot) + coalesced global store.
        // Same-wave LDS ops are in-order: no sync needed.
        const float4* Sw = (const float4*)&S[wave][0][0][0];   // 192 float4
        #pragma unroll
        for (int q = 0; q < 3; ++q) {
            int j = q * 64 + lane;            // 0..191
            int line = (j >= 96) ? 1 : 0;
            int rem = j - 96 * line;          // 0..95 = cell*6 + s
            int c = rem / 6;
            int s = rem - 6 * c;
            float4 v = Sw[line * 96 + ((c & 3) * 4 + (c >> 2)) * 6 + s];
            out4[rowf4 + (size_t)(pass * 2 + line) * 480 + rem] = v;
        }
    }
}

extern "C" void kernel_launch(void* const* d_in, const int* in_sizes, int n_in,
                              void* d_out, int out_size, void* d_ws, size_t ws_size,
                              hipStream_t stream) {
    (void)in_sizes; (void)n_in; (void)d_ws; (void)ws_size; (void)out_size;
    const float* data = (const float*)d_in[0];
    const float* cm   = (const float*)d_in[1];
    float* out        = (float*)d_out;
    const int nblocks = 128 * GRID_H;   // one block per (b, h)
    ansi_kernel<<<nblocks, 320, 0, stream>>>(data, cm, out);
}